// Round 17
// baseline (34.529 us; speedup 1.0000x reference)
//
#include <hip/hip_runtime.h>

#define Oo    32
#define F2    4096
#define GRID  256            // (oq:4) x (h:64) -> 1 block/CU
#define SLOTS 64             // per-o partial slots: one per h-row block
#define NTOT  (32 * F2)
#define WBUF  6912           // 9*64*12 dwords per w buffer
#define XBUF  7128           // 3*66*36 dwords per x buffer

typedef _Float16 h2 __attribute__((ext_vector_type(2)));
typedef _Float16 h8 __attribute__((ext_vector_type(8)));

#if __has_builtin(__builtin_amdgcn_fdot2)
#define DOT2(a, b, c) __builtin_amdgcn_fdot2((a), (b), (c), false)
#else
__device__ __forceinline__ float DOT2(h2 a, h2 b, float c) {
    return c + (float)a.x * (float)b.x + (float)a.y * (float)b.y;
}
#endif

__device__ __forceinline__ unsigned pkh2f(float a, float b) {
    h2 t; t.x = (_Float16)a; t.y = (_Float16)b;
    return __builtin_bit_cast(unsigned, t);
}
__device__ __forceinline__ h2 bch2(unsigned u) { return __builtin_bit_cast(h2, u); }

// r16 full-row tile (the DRAM-contiguity win: 42.9->32.1us) + LDS compute
// reads vectorized 4x. r16 COMPUTE did 108 scalar b32 LDS reads/thread/chunk
// (~20k serialized LDS cycles/CU = ~8.3us). Now:
//   w LDS [k:9][f:64][o':12]  -> per k, 8 o-weights = 2 ds_read_b128
//         (f-stride 12 dwords: bank starts period-8 -> 2-way = free; staging
//          writes are 4 b128 along o; slots (o4:2)x(k:9)x(fq:16) keep the
//          wave's DRAM reads 256B-contiguous)
//   x LDS [kh:3][w':66][b':36] -> per k, 4 batches = 1 ds_read_b128
//         (w' = gw+1: halos at w'=0/65 zeroed once -> tap = f+kw, no branches)
// 27 b128/thread/chunk (~10.4k cy/CU). Both buffers double-buffered -> ONE
// barrier per chunk (writes go to the opposite buffer): 6 barriers total.
// LDS 109.7KB, 1 block/CU. Channel-pair chunks + epilogue verbatim from r16.
// No min-waves launch_bounds (",N" VGPR-cap trap, r5/r7).
template <typename YT>
__global__ __launch_bounds__(512) void svconv_kernel(
    const float* __restrict__ x, const float* __restrict__ wgt,
    const float* __restrict__ bias, YT* __restrict__ y,
    float* __restrict__ psum, float* __restrict__ psumsq)
{
    __shared__ __align__(16) unsigned ldsW[2 * WBUF];   // 55.3KB
    __shared__ __align__(16) unsigned ldsX[2 * XBUF];   // 57.0KB

    const int tid = threadIdx.x;
    const int f   = tid & 63;
    const int bq  = tid >> 6;                 // 0..7
    const int oq  = blockIdx.x >> 6;          // 0..3
    const int h   = blockIdx.x & 63;
    const int col = h * 64 + f;

    // ---- weight slots: tid<288 = (o4:2)x(k:9)x(q:16 f-quads) ----
    const bool wOK = (tid < 288);
    int wg = 0, wl = 0;
    {
        int s = wOK ? tid : 0;
        int o4 = s / 144, rm = s - 144 * o4;
        int k_ = rm >> 4, q_ = rm & 15;
        wg = ((oq * 8 + o4 * 4) * 72 + k_) * F2 + h * 64 + 4 * q_;  // +j*72*F2, +cp*18*F2, pair +9*F2
        wl = (k_ * 64 + 4 * q_) * 12 + o4 * 4;                      // +i*12 per f-step
    }

    // ---- x slots: tid<384 = (kh:3)x(q:4)x(b:32) ----
    bool xOK = false;
    int xg = 0, xkh = 0, xq = 0, xb_ = 0;
    {
        int s = (tid < 384) ? tid : 0;
        xkh = s >> 7; int r = s & 127;
        xq = r >> 5; xb_ = r & 31;
        int gh = h - 1 + xkh;
        xOK = (tid < 384) && ((unsigned)gh < 64u);
        xg = xb_ * 32768 + gh * 64 + 16 * xq;        // + c*4096 at issue
    }

    float bz[8];
#pragma unroll
    for (int j = 0; j < 8; ++j) bz[j] = bias[(oq * 8 + j) * F2 + col];

    float acc[8][4];
#pragma unroll
    for (int j = 0; j < 8; ++j)
#pragma unroll
        for (int i = 0; i < 4; ++i) acc[j][i] = 0.f;

    float4 xr0[4], xr1[4], wA[4], wB[4];      // one chunk in flight

    auto ISSUEX = [&](int cp) {
        if (xOK) {
            const int c0 = xg + cp * 8192;
#pragma unroll
            for (int e = 0; e < 4; ++e) {
                xr0[e] = *(const float4*)(x + c0 + 4 * e);
                xr1[e] = *(const float4*)(x + c0 + 4096 + 4 * e);
            }
        }
    };
    auto ISSUEW = [&](int cp) {
        if (wOK) {
            const int g0 = wg + cp * 18 * F2;
#pragma unroll
            for (int j = 0; j < 4; ++j) {
                wA[j] = *(const float4*)(wgt + g0 + j * 72 * F2);
                wB[j] = *(const float4*)(wgt + g0 + j * 72 * F2 + 9 * F2);
            }
        }
    };
    auto WRITEX = [&](int buf) {             // 16 scalar b32 (b-fastest slots: 2-way banks)
        if (xOK) {
            unsigned* xd = ldsX + buf * XBUF + xkh * (66 * 36) + xb_;
#pragma unroll
            for (int e = 0; e < 4; ++e) {
                const float* a = (const float*)&xr0[e];
                const float* b = (const float*)&xr1[e];
#pragma unroll
                for (int i = 0; i < 4; ++i)
                    xd[(16 * xq + 4 * e + i + 1) * 36] = pkh2f(a[i], b[i]);
            }
        }
    };
    auto WRITEW = [&](int buf) {             // 4 ds_write_b128 along o
        if (wOK) {
            unsigned* wd = ldsW + buf * WBUF + wl;
#pragma unroll
            for (int i = 0; i < 4; ++i) {
                uint4 pk;
                pk.x = pkh2f(((const float*)&wA[0])[i], ((const float*)&wB[0])[i]);
                pk.y = pkh2f(((const float*)&wA[1])[i], ((const float*)&wB[1])[i]);
                pk.z = pkh2f(((const float*)&wA[2])[i], ((const float*)&wB[2])[i]);
                pk.w = pkh2f(((const float*)&wA[3])[i], ((const float*)&wB[3])[i]);
                *(uint4*)(wd + i * 12) = pk;
            }
        }
    };
    auto COMPUTE = [&](int buf) {
        const unsigned* wb = ldsW + buf * WBUF;
        const unsigned* xb = ldsX + buf * XBUF;
#pragma unroll
        for (int k = 0; k < 9; ++k) {
            const int kh = k / 3, kw = k - 3 * kh;
            uint4 wlo = *(const uint4*)(wb + (k * 64 + f) * 12);
            uint4 whi = *(const uint4*)(wb + (k * 64 + f) * 12 + 4);
            uint4 xu  = *(const uint4*)(xb + (kh * 66 + f + kw) * 36 + bq * 4);
            h2 wv[8] = { bch2(wlo.x), bch2(wlo.y), bch2(wlo.z), bch2(wlo.w),
                         bch2(whi.x), bch2(whi.y), bch2(whi.z), bch2(whi.w) };
            h2 xv[4] = { bch2(xu.x), bch2(xu.y), bch2(xu.z), bch2(xu.w) };
#pragma unroll
            for (int j = 0; j < 8; ++j)
#pragma unroll
                for (int i = 0; i < 4; ++i)
                    acc[j][i] = DOT2(wv[j], xv[i], acc[j][i]);
        }
    };

    // ---- prologue: zero x LDS (halos + invalid-gh rows stay zero) ----
    ISSUEX(0); ISSUEW(0);
    for (int i = tid; i < 2 * XBUF; i += 512) ldsX[i] = 0u;
    __syncthreads();
    WRITEX(0); WRITEW(0);
    ISSUEX(1); ISSUEW(1);
    __syncthreads();

#pragma unroll
    for (int cp = 0; cp < 4; ++cp) {
        if (cp < 3) { WRITEX((cp + 1) & 1); WRITEW((cp + 1) & 1); }
        if (cp < 2) { ISSUEX(cp + 2); ISSUEW(cp + 2); }
        COMPUTE(cp & 1);
        __syncthreads();
    }

    // ---- epilogue: bias, y store, BN partials (verbatim r16) ----
    float s_[8], ss_[8];
#pragma unroll
    for (int j = 0; j < 8; ++j) {
        s_[j] = 0.f; ss_[j] = 0.f;
#pragma unroll
        for (int i = 0; i < 4; ++i) {
            float a = acc[j][i] + bz[j];
            y[(size_t)((bq * 4 + i) * Oo + oq * 8 + j) * F2 + col] = (YT)a;
            s_[j] += a; ss_[j] = fmaf(a, a, ss_[j]);
        }
    }
    if (psum != nullptr) {
#pragma unroll
        for (int j = 0; j < 8; ++j)
#pragma unroll
            for (int d = 32; d >= 1; d >>= 1) {
                s_[j]  += __shfl_down(s_[j],  d, 64);
                ss_[j] += __shfl_down(ss_[j], d, 64);
            }
        float* scr = (float*)ldsX;          // [2][bq:8][o:8]
        if (f == 0) {
#pragma unroll
            for (int j = 0; j < 8; ++j) {
                scr[bq * 8 + j]      = s_[j];
                scr[64 + bq * 8 + j] = ss_[j];
            }
        }
        __syncthreads();
        if (tid < 64) {
            int j = tid >> 3, g = tid & 7;  // g = bq
            float v  = scr[g * 8 + j];
            float vv = scr[64 + g * 8 + j];
#pragma unroll
            for (int d = 4; d >= 1; d >>= 1) {
                v  += __shfl_down(v,  d, 8);
                vv += __shfl_down(vv, d, 8);
            }
            if (g == 0) {
                psum[(oq * 8 + j) * SLOTS + h]   = v;
                psumsq[(oq * 8 + j) * SLOTS + h] = vv;
            }
        }
    }
}

__global__ __launch_bounds__(64) void bnstats_kernel(
    const float* __restrict__ psum, const float* __restrict__ psumsq,
    const float* __restrict__ gamma, const float* __restrict__ beta,
    float* __restrict__ scsh)
{
    const int o = blockIdx.x;
    const int t = threadIdx.x;
    float s  = psum[o * SLOTS + t];
    float ss = psumsq[o * SLOTS + t];
#pragma unroll
    for (int d = 32; d >= 1; d >>= 1) {
        s  += __shfl_down(s, d, 64);
        ss += __shfl_down(ss, d, 64);
    }
    if (t == 0) {
        float mean = s / (float)NTOT;
        float var  = ss / (float)NTOT - mean * mean;
        float rstd = rsqrtf(var + 1e-5f);
        float scl  = gamma[o] * rstd;
        scsh[o]      = scl;
        scsh[Oo + o] = beta[o] - mean * scl;
    }
}

// ---- primary apply: read f16 y from ws, write fp32 to d_out ----
__global__ __launch_bounds__(256) void bnapply_f16_kernel(
    const _Float16* __restrict__ yh, const float* __restrict__ scsh,
    float* __restrict__ y)
{
    int i = blockIdx.x * 256 + threadIdx.x;    // 8-element packs; 524288 total
    h8 v = ((const h8*)yh)[i];
    int o = (i >> 9) & 31;
    float scl = scsh[o], sh = scsh[Oo + o];
    float4 lo, hi;
    lo.x = fmaf((float)v[0], scl, sh);
    lo.y = fmaf((float)v[1], scl, sh);
    lo.z = fmaf((float)v[2], scl, sh);
    lo.w = fmaf((float)v[3], scl, sh);
    hi.x = fmaf((float)v[4], scl, sh);
    hi.y = fmaf((float)v[5], scl, sh);
    hi.z = fmaf((float)v[6], scl, sh);
    hi.w = fmaf((float)v[7], scl, sh);
    ((float4*)y)[2 * i]     = lo;
    ((float4*)y)[2 * i + 1] = hi;
}

// ---- fallback apply: fp32 in place ----
__global__ __launch_bounds__(256) void bnapply_kernel(
    float* __restrict__ y, const float* __restrict__ scsh)
{
    int i = blockIdx.x * 256 + threadIdx.x;    // float4 index
    float4 v = ((const float4*)y)[i];
    int o = (i >> 10) & 31;
    float scl = scsh[o], sh = scsh[Oo + o];
    v.x = fmaf(v.x, scl, sh);
    v.y = fmaf(v.y, scl, sh);
    v.z = fmaf(v.z, scl, sh);
    v.w = fmaf(v.w, scl, sh);
    ((float4*)y)[i] = v;
}

// ---- tiny-scratch stats fallback: reduce y directly ----
__global__ __launch_bounds__(256) void bnreduce_y_kernel(
    const float* __restrict__ y, float* __restrict__ seg, float* __restrict__ segsq)
{
    const int o  = blockIdx.x >> 3;
    const int sg = blockIdx.x & 7;
    const int t  = threadIdx.x;
    float s = 0.f, ss = 0.f;
    for (int i = t; i < 4 * 1024; i += 256) {
        int b   = sg * 4 + (i >> 10);
        int fof = (i & 1023) * 4;
        float4 v = *(const float4*)(y + (size_t)(b * Oo + o) * F2 + fof);
        s  += (v.x + v.y) + (v.z + v.w);
        ss += v.x * v.x + v.y * v.y + v.z * v.z + v.w * v.w;
    }
#pragma unroll
    for (int d = 32; d >= 1; d >>= 1) {
        s  += __shfl_down(s, d, 64);
        ss += __shfl_down(ss, d, 64);
    }
    __shared__ float ls[4], lss[4];
    int wv = t >> 6, ln = t & 63;
    if (ln == 0) { ls[wv] = s; lss[wv] = ss; }
    __syncthreads();
    if (t == 0) {
        seg[blockIdx.x]   = (ls[0] + ls[1]) + (ls[2] + ls[3]);
        segsq[blockIdx.x] = (lss[0] + lss[1]) + (lss[2] + lss[3]);
    }
}

__global__ __launch_bounds__(256) void bnstats2_kernel(
    const float* __restrict__ seg, const float* __restrict__ segsq,
    const float* __restrict__ gamma, const float* __restrict__ beta,
    float* __restrict__ scsh)
{
    const int t = threadIdx.x;
    const int o = t >> 3, g = t & 7;
    float v  = seg[t];
    float vv = segsq[t];
#pragma unroll
    for (int d = 4; d >= 1; d >>= 1) {
        v  += __shfl_down(v,  d, 8);
        vv += __shfl_down(vv, d, 8);
    }
    if (g == 0) {
        float mean = v / (float)NTOT;
        float var  = vv / (float)NTOT - mean * mean;
        float rstd = rsqrtf(var + 1e-5f);
        float scl  = gamma[o] * rstd;
        scsh[o]      = scl;
        scsh[Oo + o] = beta[o] - mean * scl;
    }
}

extern "C" void kernel_launch(void* const* d_in, const int* in_sizes, int n_in,
                              void* d_out, int out_size, void* d_ws, size_t ws_size,
                              hipStream_t stream)
{
    const float* x     = (const float*)d_in[0];
    const float* wgt   = (const float*)d_in[1];
    const float* bias  = (const float*)d_in[2];
    const float* gamma = (const float*)d_in[3];
    const float* beta  = (const float*)d_in[4];
    float* y = (float*)d_out;

    const size_t n_elems    = (size_t)NTOT * Oo;              // 4,194,304
    const size_t yh_bytes   = n_elems * sizeof(_Float16);     // 8 MiB
    const size_t psum_bytes = (size_t)(2 * Oo * SLOTS + 2 * Oo) * sizeof(float);

    if (ws_size >= yh_bytes + psum_bytes) {
        // primary: f16 intermediate y in ws
        _Float16* yh  = (_Float16*)d_ws;
        float* psum   = (float*)((char*)d_ws + yh_bytes);     // [Oo][SLOTS]
        float* psumsq = psum + Oo * SLOTS;
        float* scsh   = psumsq + Oo * SLOTS;                  // [2][Oo]
        svconv_kernel<_Float16><<<GRID, 512, 0, stream>>>(x, wgt, bias, yh, psum, psumsq);
        bnstats_kernel<<<Oo, 64, 0, stream>>>(psum, psumsq, gamma, beta, scsh);
        bnapply_f16_kernel<<<(int)(n_elems / 8 / 256), 256, 0, stream>>>(yh, scsh, y);
    } else if (ws_size >= psum_bytes) {
        // secondary: fp32 y in d_out, partials in ws
        float* psum   = (float*)d_ws;
        float* psumsq = psum + Oo * SLOTS;
        float* scsh   = psumsq + Oo * SLOTS;
        svconv_kernel<float><<<GRID, 512, 0, stream>>>(x, wgt, bias, y, psum, psumsq);
        bnstats_kernel<<<Oo, 64, 0, stream>>>(psum, psumsq, gamma, beta, scsh);
        bnapply_kernel<<<(int)(n_elems / 4 / 256), 256, 0, stream>>>(y, scsh);
    } else {
        // tertiary: tiny scratch — reduce y directly
        float* seg   = (float*)d_ws;                          // [256]
        float* segsq = seg + 256;
        float* scsh  = segsq + 256;
        svconv_kernel<float><<<GRID, 512, 0, stream>>>(x, wgt, bias, y, nullptr, nullptr);
        bnreduce_y_kernel<<<256, 256, 0, stream>>>(y, seg, segsq);
        bnstats2_kernel<<<1, 256, 0, stream>>>(seg, segsq, gamma, beta, scsh);
        bnapply_kernel<<<(int)(n_elems / 4 / 256), 256, 0, stream>>>(y, scsh);
    }
}